// Round 4
// baseline (43.260 us; speedup 1.0000x reference)
//
#include <hip/hip_runtime.h>
#include <math.h>

// SMEFTNet forward, lanes-over-i + readlane j-broadcast. B=128, N=128, H=16.
//
// Layout: grid 256 = (batch, ihalf); 256 thr = 4 waves, wave w owns j-slice
// [32w, 32w+32). Lane l owns node i = ihalf*64+l AND carries j-payload for
// j = 32w + (l&31) in its registers. The j-loop broadcasts payload via
// v_readlane (uniform index) -> SGPR operands; zero LDS in the main loop.
// Cross-wave A-partials merged via LDS (stride-1, conflict-free), then the
// per-node tail (2nd MLP layer, rotation, proj/readout-partials) per lane.

#define BB 128
#define NN 128
#define BN (BB * NN)

#define RL(x, l) __int_as_float(__builtin_amdgcn_readlane(__float_as_int(x), (l)))

template <int CTRL>
__device__ __forceinline__ float dpp_add(float x) {
    int t = __builtin_amdgcn_update_dpp(0, __float_as_int(x), CTRL, 0xF, 0xF, true);
    return x + __int_as_float(t);
}

__device__ __forceinline__ float wave_sum64(float x) {
    x = dpp_add<0xB1>(x);   // quad_perm [1,0,3,2]
    x = dpp_add<0x4E>(x);   // quad_perm [2,3,0,1]
    x = dpp_add<0x114>(x);  // row_shr:4
    x = dpp_add<0x118>(x);  // row_shr:8
    x = dpp_add<0x142>(x);  // row_bcast15
    x = dpp_add<0x143>(x);  // row_bcast31
    return __int_as_float(__builtin_amdgcn_readlane(__float_as_int(x), 63));
}

// ---------------- K1: conv0 + proj for conv1 ----------------
__global__ __launch_bounds__(256, 1) void conv0_kernel(
    const float* __restrict__ ang,   // (B,N,2)
    const float* __restrict__ w0,    // c0_w0 (5,16)
    const float* __restrict__ b0,    // (16)
    const float* __restrict__ w1,    // c0_w1 (16,17)
    const float* __restrict__ b1,    // (17)
    const float* __restrict__ nw0,   // c1_w0 (50,16)
    const float* __restrict__ nb0,   // c1_b0 (16)
    float* __restrict__ ang1,        // (BN,2)
    float* __restrict__ u1,          // (BN,16)
    float* __restrict__ v1)          // (BN,16)
{
    const int tid  = threadIdx.x;
    const int lane = tid & 63;
    const int wid  = tid >> 6;
    const int b     = blockIdx.x >> 1;
    const int ihalf = blockIdx.x & 1;
    const int nodebase = b * NN;
    const int ni = nodebase + ihalf * 64 + lane;

    __shared__ float Ap[4][17][64];

    // my node i
    const float2 ai = ((const float2*)ang)[ni];
    const float r2i = fmaf(ai.x, ai.x, ai.y * ai.y);
    const float abszi = __builtin_amdgcn_sqrtf(r2i);
    const float invi = __builtin_amdgcn_rsqf(r2i);

    // j payload in registers (lane&31 within this wave's 32-j slice)
    const int jbase = wid * 32;
    const float2 aj = ((const float2*)ang)[nodebase + jbase + (lane & 31)];
    const float r2j = fmaf(aj.x, aj.x, aj.y * aj.y);
    const float jre = aj.x, jim = aj.y;
    const float jab = __builtin_amdgcn_sqrtf(r2j);
    const float jiv = __builtin_amdgcn_rsqf(r2j);

    // layer-0 row precompute
    float u0b[16], q0[16], wc[16], wsn[16];
    #pragma unroll
    for (int k = 0; k < 16; ++k) {
        u0b[k] = fmaf(abszi, w0[k] - w0[32 + k], b0[k]);  // absz*(Wa-Wc)+b0
        q0[k]  = w0[16 + k] + w0[32 + k];                 // Wb+Wc
        wc[k]  = w0[48 + k];
        wsn[k] = w0[64 + k];
    }

    float A[16];
    #pragma unroll
    for (int k = 0; k < 16; ++k) A[k] = 0.0f;
    float degf = 0.0f;

    #pragma unroll 8
    for (int jj = 0; jj < 32; ++jj) {
        const float s_re = RL(jre, jj), s_im = RL(jim, jj);
        const float s_ab = RL(jab, jj), s_iv = RL(jiv, jj);
        float dre = ai.x - s_re, dim = ai.y - s_im;
        float d2 = fmaf(dre, dre, dim * dim);
        float adjf = (d2 <= 0.16f) ? 1.0f : 0.0f;
        degf += adjf;
        float inv = invi * s_iv;
        float cosv = fmaf(ai.x, s_re, ai.y * s_im) * inv;
        float sinv = fmaf(ai.y, s_re, -(ai.x * s_im)) * inv;
        #pragma unroll
        for (int k = 0; k < 16; ++k) {
            float z = fmaf(s_ab, q0[k], u0b[k]);
            z = fmaf(cosv, wc[k], z);
            z = fmaf(sinv, wsn[k], z);
            float a = fmaxf(z, 0.01f * z);
            A[k] = fmaf(a, adjf, A[k]);
        }
    }

    // cross-wave partial merge (stride-1 over lanes, conflict-free)
    #pragma unroll
    for (int k = 0; k < 16; ++k) Ap[wid][k][lane] = A[k];
    Ap[wid][16][lane] = degf;
    __syncthreads();
    #pragma unroll
    for (int w2 = 0; w2 < 4; ++w2) {
        if (w2 == wid) continue;
        #pragma unroll
        for (int k = 0; k < 16; ++k) A[k] += Ap[w2][k][lane];
        degf += Ap[w2][16][lane];
    }

    // per-node second MLP layer
    const float invdeg = __builtin_amdgcn_rcpf(degf);
    float m[17];
    #pragma unroll
    for (int t = 0; t < 17; ++t) {
        float s = 0.0f;
        #pragma unroll
        for (int k = 0; k < 16; ++k) s = fmaf(A[k], w1[k * 17 + t], s);
        m[t] = fmaf(s, invdeg, b1[t]);
    }

    if (wid == 0) {  // rotated angles for conv1 (v_cos/v_sin take revolutions)
        float g = m[16] - floorf(m[16]);
        float cs = __builtin_amdgcn_cosf(g);
        float sn = __builtin_amdgcn_sinf(g);
        float re2 = cs * ai.x - sn * ai.y;
        float im2 = fmaf(sn, ai.x, cs * ai.y);
        ((float2*)ang1)[ni] = make_float2(re2, im2);
    }

    // proj for conv1: wid 0/1 -> u1 halves, wid 2/3 -> v1 halves
    const int isV = wid >> 1;
    const int khalf = wid & 1;
    float acc[8];
    if (isV == 0) {
        #pragma unroll
        for (int kk = 0; kk < 8; ++kk) {
            const int kp = khalf * 8 + kk;
            float a = nb0[kp];
            #pragma unroll
            for (int c = 0; c < 16; ++c) {
                a = fmaf(m[c], nw0[c * 16 + kp], a);          // +Wa
                a = fmaf(-m[c], nw0[512 + c * 16 + kp], a);   // -Wc
            }
            acc[kk] = a;
        }
        float4* up = (float4*)(u1 + (size_t)ni * 16);
        up[khalf * 2 + 0] = make_float4(acc[0], acc[1], acc[2], acc[3]);
        up[khalf * 2 + 1] = make_float4(acc[4], acc[5], acc[6], acc[7]);
    } else {
        #pragma unroll
        for (int kk = 0; kk < 8; ++kk) {
            const int kp = khalf * 8 + kk;
            float a = 0.0f;
            #pragma unroll
            for (int c = 0; c < 16; ++c) {
                a = fmaf(m[c], nw0[256 + c * 16 + kp], a);    // +Wb
                a = fmaf(m[c], nw0[512 + c * 16 + kp], a);    // +Wc
            }
            acc[kk] = a;
        }
        float4* vp = (float4*)(v1 + (size_t)ni * 16);
        vp[khalf * 2 + 0] = make_float4(acc[0], acc[1], acc[2], acc[3]);
        vp[khalf * 2 + 1] = make_float4(acc[4], acc[5], acc[6], acc[7]);
    }
}

// ---------------- K2: conv1 + partial readout ----------------
__global__ __launch_bounds__(256, 1) void conv1_kernel(
    const float* __restrict__ pt,    // (B,N)
    const float* __restrict__ ang1,  // (BN,2)
    const float* __restrict__ u1,    // (BN,16)
    const float* __restrict__ v1,    // (BN,16)
    const float* __restrict__ w0,    // c1_w0 (50,16)
    const float* __restrict__ w1,    // c1_w1 (16,17)
    const float* __restrict__ b1,    // (17)
    float* __restrict__ part)        // (256,20): [0]=Σptf, [1..18]=Σptf*y
{
    const int tid  = threadIdx.x;
    const int lane = tid & 63;
    const int wid  = tid >> 6;
    const int b     = blockIdx.x >> 1;
    const int ihalf = blockIdx.x & 1;
    const int nodebase = b * NN;
    const int ni = nodebase + ihalf * 64 + lane;

    __shared__ float Ap[4][17][64];

    // my node i
    const float2 ai = ((const float2*)ang1)[ni];
    const float r2i = fmaf(ai.x, ai.x, ai.y * ai.y);
    const float invi = __builtin_amdgcn_rsqf(r2i);
    float u0b[16];
    {
        const float4* ug = (const float4*)(u1 + (size_t)ni * 16);
        float4 a0 = ug[0], a1 = ug[1], a2 = ug[2], a3 = ug[3];
        u0b[0] = a0.x; u0b[1] = a0.y; u0b[2]  = a0.z; u0b[3]  = a0.w;
        u0b[4] = a1.x; u0b[5] = a1.y; u0b[6]  = a1.z; u0b[7]  = a1.w;
        u0b[8] = a2.x; u0b[9] = a2.y; u0b[10] = a2.z; u0b[11] = a2.w;
        u0b[12] = a3.x; u0b[13] = a3.y; u0b[14] = a3.z; u0b[15] = a3.w;
    }
    float ptf = 0.0f;
    if (wid == 0) ptf = pt[ni];

    // j payload in registers
    const int jbase = wid * 32;
    const int jnode = nodebase + jbase + (lane & 31);
    const float2 aj = ((const float2*)ang1)[jnode];
    const float r2j = fmaf(aj.x, aj.x, aj.y * aj.y);
    const float jre = aj.x, jim = aj.y;
    const float jiv = __builtin_amdgcn_rsqf(r2j);
    float pv[16];
    {
        const float4* vg = (const float4*)(v1 + (size_t)jnode * 16);
        float4 a0 = vg[0], a1 = vg[1], a2 = vg[2], a3 = vg[3];
        pv[0] = a0.x; pv[1] = a0.y; pv[2]  = a0.z; pv[3]  = a0.w;
        pv[4] = a1.x; pv[5] = a1.y; pv[6]  = a1.z; pv[7]  = a1.w;
        pv[8] = a2.x; pv[9] = a2.y; pv[10] = a2.z; pv[11] = a2.w;
        pv[12] = a3.x; pv[13] = a3.y; pv[14] = a3.z; pv[15] = a3.w;
    }

    float wc[16], wsn[16];
    #pragma unroll
    for (int k = 0; k < 16; ++k) { wc[k] = w0[768 + k]; wsn[k] = w0[784 + k]; }

    float A[16];
    #pragma unroll
    for (int k = 0; k < 16; ++k) A[k] = 0.0f;
    float degf = 0.0f;

    #pragma unroll 8
    for (int jj = 0; jj < 32; ++jj) {
        const float s_re = RL(jre, jj), s_im = RL(jim, jj), s_iv = RL(jiv, jj);
        float dre = ai.x - s_re, dim = ai.y - s_im;
        float d2 = fmaf(dre, dre, dim * dim);
        float adjf = (d2 <= 0.16f) ? 1.0f : 0.0f;
        degf += adjf;
        float inv = invi * s_iv;
        float cosv = fmaf(ai.x, s_re, ai.y * s_im) * inv;
        float sinv = fmaf(ai.y, s_re, -(ai.x * s_im)) * inv;
        #pragma unroll
        for (int k = 0; k < 16; ++k) {
            float z = u0b[k] + RL(pv[k], jj);
            z = fmaf(cosv, wc[k], z);
            z = fmaf(sinv, wsn[k], z);
            float a = fmaxf(z, 0.01f * z);
            A[k] = fmaf(a, adjf, A[k]);
        }
    }

    #pragma unroll
    for (int k = 0; k < 16; ++k) Ap[wid][k][lane] = A[k];
    Ap[wid][16][lane] = degf;
    __syncthreads();

    if (wid == 0) {
        #pragma unroll
        for (int w2 = 1; w2 < 4; ++w2) {
            #pragma unroll
            for (int k = 0; k < 16; ++k) A[k] += Ap[w2][k][lane];
            degf += Ap[w2][16][lane];
        }
        const float invdeg = __builtin_amdgcn_rcpf(degf);
        float m[17];
        #pragma unroll
        for (int t = 0; t < 17; ++t) {
            float s = 0.0f;
            #pragma unroll
            for (int k = 0; k < 16; ++k) s = fmaf(A[k], w1[k * 17 + t], s);
            m[t] = fmaf(s, invdeg, b1[t]);
        }
        float g = m[16] - floorf(m[16]);
        float cs = __builtin_amdgcn_cosf(g);
        float sn = __builtin_amdgcn_sinf(g);
        float re2 = cs * ai.x - sn * ai.y;
        float im2 = fmaf(sn, ai.x, cs * ai.y);

        float* pout = part + (size_t)blockIdx.x * 20;
        float s0 = wave_sum64(ptf);
        if (lane == 0) pout[0] = s0;
        #pragma unroll
        for (int f = 0; f < 16; ++f) {
            float sf = wave_sum64(ptf * m[f]);
            if (lane == 0) pout[1 + f] = sf;
        }
        float sre = wave_sum64(ptf * re2);
        float sim = wave_sum64(ptf * im2);
        if (lane == 0) { pout[17] = sre; pout[18] = sim; }
    }
}

// ---------------- K3: final readout ----------------
__global__ __launch_bounds__(64) void readout_kernel(
    const float* __restrict__ part,  // (256,20)
    const float* __restrict__ w0, const float* __restrict__ b0,  // (16,32),(32)
    const float* __restrict__ w1, const float* __restrict__ b1,  // (32,32),(32)
    const float* __restrict__ w2, const float* __restrict__ b2,  // (32,1),(1)
    float* __restrict__ out) {
    const int b = blockIdx.x;
    const int t = threadIdx.x;
    const float* p0 = part + (size_t)(2 * b) * 20;
    const float* p1 = p0 + 20;

    __shared__ float xg[18];
    __shared__ float h1s[32];

    float denom = p0[0] + p1[0];
    float invd = (denom > 0.0f) ? __builtin_amdgcn_rcpf(denom) : 0.0f;
    if (t < 18) xg[t] = (p0[1 + t] + p1[1 + t]) * invd;
    __syncthreads();

    if (t < 32) {
        float h = b0[t];
        #pragma unroll
        for (int k = 0; k < 16; ++k) h = fmaf(xg[k], w0[k * 32 + t], h);
        h = fmaxf(h, 0.01f * h);
        h1s[t] = h;
    }
    __syncthreads();
    if (t < 32) {
        float h = b1[t];
        #pragma unroll
        for (int k = 0; k < 32; ++k) h = fmaf(h1s[k], w1[k * 32 + t], h);
        h = fmaxf(h, 0.01f * h);
        float p = h * w2[t];
        #pragma unroll
        for (int off = 16; off; off >>= 1) p += __shfl_xor(p, off, 32);
        if (t == 0) {
            out[b * 3 + 0] = 1.0f / (1.0f + expf(-(p + b2[0])));
            out[b * 3 + 1] = xg[16];
            out[b * 3 + 2] = xg[17];
        }
    }
}

extern "C" void kernel_launch(void* const* d_in, const int* in_sizes, int n_in,
                              void* d_out, int out_size, void* d_ws, size_t ws_size,
                              hipStream_t stream) {
    const float* pt    = (const float*)d_in[0];
    const float* ang   = (const float*)d_in[1];
    const float* c0_w0 = (const float*)d_in[2];
    const float* c0_b0 = (const float*)d_in[3];
    const float* c0_w1 = (const float*)d_in[4];
    const float* c0_b1 = (const float*)d_in[5];
    const float* c1_w0 = (const float*)d_in[6];
    const float* c1_b0 = (const float*)d_in[7];
    const float* c1_w1 = (const float*)d_in[8];
    const float* c1_b1 = (const float*)d_in[9];
    const float* r_w0  = (const float*)d_in[10];
    const float* r_b0  = (const float*)d_in[11];
    const float* r_w1  = (const float*)d_in[12];
    const float* r_b1  = (const float*)d_in[13];
    const float* r_w2  = (const float*)d_in[14];
    const float* r_b2  = (const float*)d_in[15];
    float* out = (float*)d_out;
    float* ws = (float*)d_ws;

    float* ang1 = ws;                          // BN*2
    float* u1   = ang1 + (size_t)BN * 2;       // BN*16
    float* v1   = u1 + (size_t)BN * 16;        // BN*16
    float* partb = v1 + (size_t)BN * 16;       // 256*20

    hipLaunchKernelGGL(conv0_kernel, dim3(256), dim3(256), 0, stream,
                       ang, c0_w0, c0_b0, c0_w1, c0_b1, c1_w0, c1_b0,
                       ang1, u1, v1);
    hipLaunchKernelGGL(conv1_kernel, dim3(256), dim3(256), 0, stream,
                       pt, ang1, u1, v1, c1_w0, c1_w1, c1_b1, partb);
    hipLaunchKernelGGL(readout_kernel, dim3(BB), dim3(64), 0, stream,
                       partb, r_w0, r_b0, r_w1, r_b1, r_w2, r_b2, out);
}

// Round 5
// 35.117 us; speedup vs baseline: 1.2319x; 1.2319x over previous
//
#include <hip/hip_runtime.h>
#include <math.h>

// SMEFTNet forward. B=128, N=128, H=16.
// Structure = the verified 37µs wave-per-node version (R2-bench), with the
// 16-channel inner loop rewritten as f32x2 packed ops -> v_pk_fma_f32.
//
//   w[i][j] = adj/deg_i (pt_i cancels; diag adj=1 => sw==1)
//   agg[t]  = (1/deg) * sum_k (sum_j adj*leaky(z_jk)) * w1[k][t] + b1[t]
//   conv0 h = absz (rank-1) -> no per-node proj arrays needed
//   conv0 epilogue fuses proj for conv1: u1 = b0'+h1@(Wa-Wc), v1 = h1@(Wb+Wc)

#define BB 128
#define NN 128
#define BN (BB * NN)

typedef float f32x2 __attribute__((ext_vector_type(2)));

__device__ __forceinline__ f32x2 pk2(float s) { f32x2 r; r[0] = s; r[1] = s; return r; }
__device__ __forceinline__ f32x2 pkfma(f32x2 a, f32x2 b, f32x2 c) {
    return __builtin_elementwise_fma(a, b, c);
}
__device__ __forceinline__ f32x2 pkmax(f32x2 a, f32x2 b) {
    return __builtin_elementwise_max(a, b);
}

template <int CTRL>
__device__ __forceinline__ float dpp_add(float x) {
    int t = __builtin_amdgcn_update_dpp(0, __float_as_int(x), CTRL, 0xF, 0xF, true);
    return x + __int_as_float(t);
}

// Sum across 64 lanes; returns wave-uniform value.
__device__ __forceinline__ float wave_sum64(float x) {
    x = dpp_add<0xB1>(x);   // quad_perm [1,0,3,2]
    x = dpp_add<0x4E>(x);   // quad_perm [2,3,0,1]
    x = dpp_add<0x114>(x);  // row_shr:4
    x = dpp_add<0x118>(x);  // row_shr:8
    x = dpp_add<0x142>(x);  // row_bcast15
    x = dpp_add<0x143>(x);  // row_bcast31
    return __int_as_float(__builtin_amdgcn_readlane(__float_as_int(x), 63));
}

// One wave per node i; lanes handle j = lane and lane+64. 4 waves/block.
template <int L>
__global__ __launch_bounds__(256) void conv_kernel(
    const float* __restrict__ ang,   // (BN,2): input ang (L0) or ang1 (L1)
    const float* __restrict__ u,     // L1: u1 (BN,16)
    const float* __restrict__ v,     // L1: v1 (BN,16)
    const float* __restrict__ w0,    // L0: c0_w0 (5,16); L1: c1_w0 (50,16)
    const float* __restrict__ b0,    // L0 only
    const float* __restrict__ w1,    // (16,17)
    const float* __restrict__ b1,    // (17)
    const float* __restrict__ nw0,   // L0 only: c1_w0 (50,16) for fused proj
    const float* __restrict__ nb0,   // L0 only: c1_b0 (16)
    float* __restrict__ out_u,       // L0
    float* __restrict__ out_v,       // L0
    float* __restrict__ out_ang,     // L0: ang1 (BN,2)
    float* __restrict__ y)           // L1: (BN,18) = [h(16), re2, im2]
{
    const int lane = threadIdx.x & 63;
    const int wid  = threadIdx.x >> 6;
    const int ni   = __builtin_amdgcn_readfirstlane(blockIdx.x * 4 + wid);
    const int base = ni & ~(NN - 1);

    const float2 aiv = ((const float2*)ang)[ni];   // uniform -> s_load
    const float rei = aiv.x, imi = aiv.y;
    const float r2i = fmaf(rei, rei, imi * imi);

    constexpr int cosrow = (L == 0) ? 3 : 48;

    // wave-uniform channel-pair constants
    f32x2 u0b2[8], q02[8], wc2[8], ws2[8];
    if constexpr (L == 0) {
        const float abszi = __builtin_amdgcn_sqrtf(r2i);
        #pragma unroll
        for (int p = 0; p < 8; ++p) {
            f32x2 wa = *(const f32x2*)(w0 + 2 * p);
            f32x2 wb = *(const f32x2*)(w0 + 16 + 2 * p);
            f32x2 wcv = *(const f32x2*)(w0 + 32 + 2 * p);
            f32x2 bb = *(const f32x2*)(b0 + 2 * p);
            u0b2[p] = pkfma(pk2(abszi), wa - wcv, bb);   // absz_i*(Wa-Wc)+b0
            q02[p]  = wb + wcv;                          // Wb+Wc
            wc2[p]  = *(const f32x2*)(w0 + cosrow * 16 + 2 * p);
            ws2[p]  = *(const f32x2*)(w0 + (cosrow + 1) * 16 + 2 * p);
        }
    } else {
        #pragma unroll
        for (int p = 0; p < 8; ++p) {
            f32x2 uu; uu[0] = u[ni * 16 + 2 * p]; uu[1] = u[ni * 16 + 2 * p + 1];
            u0b2[p] = uu;                                 // uniform -> s_load
            wc2[p]  = *(const f32x2*)(w0 + cosrow * 16 + 2 * p);
            ws2[p]  = *(const f32x2*)(w0 + (cosrow + 1) * 16 + 2 * p);
        }
    }

    f32x2 A2[8];
    #pragma unroll
    for (int p = 0; p < 8; ++p) A2[p] = pk2(0.0f);
    int deg = 0;

    #pragma unroll
    for (int jj = 0; jj < 2; ++jj) {
        const int nj = base + lane + jj * 64;
        const float2 ajv = ((const float2*)ang)[nj];
        const float rej = ajv.x, imj = ajv.y;

        const float dre = rei - rej, dim = imi - imj;
        const float d2 = fmaf(dre, dre, dim * dim);
        const bool isadj = (d2 <= 0.16f);
        deg += (int)__popcll(__ballot(isadj));
        const f32x2 adj2 = pk2(isadj ? 1.0f : 0.0f);

        const float r2j = fmaf(rej, rej, imj * imj);
        const float inv = fminf(rsqrtf(r2i * r2j), 1e12f);
        const f32x2 cos2 = pk2(fmaf(rei, rej, imi * imj) * inv);
        const f32x2 sin2 = pk2(fmaf(imi, rej, -(rei * imj)) * inv);

        f32x2 vj2[8];
        f32x2 ab2;
        if constexpr (L == 0) {
            ab2 = pk2(__builtin_amdgcn_sqrtf(r2j));
        } else {
            const float4* vp = (const float4*)(v + (size_t)nj * 16);
            float4 a0 = vp[0], a1 = vp[1], a2 = vp[2], a3 = vp[3];
            vj2[0][0] = a0.x; vj2[0][1] = a0.y; vj2[1][0] = a0.z; vj2[1][1] = a0.w;
            vj2[2][0] = a1.x; vj2[2][1] = a1.y; vj2[3][0] = a1.z; vj2[3][1] = a1.w;
            vj2[4][0] = a2.x; vj2[4][1] = a2.y; vj2[5][0] = a2.z; vj2[5][1] = a2.w;
            vj2[6][0] = a3.x; vj2[6][1] = a3.y; vj2[7][0] = a3.z; vj2[7][1] = a3.w;
        }

        #pragma unroll
        for (int p = 0; p < 8; ++p) {
            f32x2 z;
            if constexpr (L == 0) z = pkfma(ab2, q02[p], u0b2[p]);
            else                  z = u0b2[p] + vj2[p];
            z = pkfma(cos2, wc2[p], z);
            z = pkfma(sin2, ws2[p], z);
            f32x2 a = pkmax(z, z * 0.01f);   // leaky relu
            A2[p] = pkfma(a, adj2, A2[p]);   // masked accumulate
        }
    }

    // cross-lane reduce: 16 channels -> wave-uniform values
    float Ak[16];
    #pragma unroll
    for (int p = 0; p < 8; ++p) {
        Ak[2 * p]     = wave_sum64(A2[p][0]);
        Ak[2 * p + 1] = wave_sum64(A2[p][1]);
    }
    const float invdeg = __builtin_amdgcn_rcpf((float)deg);

    // per-node second MLP layer: lanes 0..16 each own one output channel
    float aggv = 0.0f;
    if (lane < 17) {
        float s = 0.0f;
        #pragma unroll
        for (int k = 0; k < 16; ++k) s = fmaf(Ak[k], w1[k * 17 + lane], s);
        aggv = fmaf(s, invdeg, b1[lane]);
    }

    __shared__ float h1s[4][16];

    if constexpr (L == 0) {
        if (lane < 16) h1s[wid][lane] = aggv;
        if (lane == 16) {   // gamma -> rotated ang (v_cos/v_sin in revolutions)
            float g = aggv - floorf(aggv);
            float cs = __builtin_amdgcn_cosf(g);
            float sn = __builtin_amdgcn_sinf(g);
            float re2 = cs * rei - sn * imi;
            float im2 = fmaf(sn, rei, cs * imi);
            ((float2*)out_ang)[ni] = make_float2(re2, im2);
        }
        __syncthreads();
        // fused proj for conv1: lanes 0..15 -> u1[k], lanes 16..31 -> v1[k]
        if (lane < 32) {
            const int k = lane & 15;
            const bool isU = lane < 16;
            const int off = isU ? 0 : 256;           // Wa block vs Wb block
            const float sgn = isU ? -1.0f : 1.0f;    // -Wc vs +Wc
            float acc = isU ? nb0[k] : 0.0f;
            #pragma unroll
            for (int c = 0; c < 16; ++c) {
                float wa  = nw0[off + c * 16 + k];
                float wcv = nw0[512 + c * 16 + k];
                acc = fmaf(h1s[wid][c], fmaf(sgn, wcv, wa), acc);
            }
            if (isU) out_u[ni * 16 + k] = acc;
            else     out_v[ni * 16 + k] = acc;
        }
    } else {
        if (lane < 16) y[ni * 18 + lane] = aggv;
        if (lane == 16) {
            float g = aggv - floorf(aggv);
            float cs = __builtin_amdgcn_cosf(g);
            float sn = __builtin_amdgcn_sinf(g);
            y[ni * 18 + 16] = cs * rei - sn * imi;
            y[ni * 18 + 17] = fmaf(sn, rei, cs * imi);
        }
    }
}

// One block per batch b; 128 threads (one per node).
__global__ __launch_bounds__(128) void readout_kernel(
    const float* __restrict__ pt,  // (B,N): ptf == pt since sw==1
    const float* __restrict__ y,   // (B,N,18)
    const float* __restrict__ w0, const float* __restrict__ b0,  // (16,32),(32)
    const float* __restrict__ w1, const float* __restrict__ b1,  // (32,32),(32)
    const float* __restrict__ w2, const float* __restrict__ b2,  // (32,1),(1)
    float* __restrict__ out) {
    int b = blockIdx.x;
    int tid = threadIdx.x;
    int n = b * NN + tid;
    float ptf = pt[n];
    const float* yn = y + (size_t)n * 18;

    __shared__ float sred[2][18];
    __shared__ float xg[18];
    __shared__ float h1s[32];

    float tot = ptf;
#pragma unroll
    for (int off = 32; off; off >>= 1) tot += __shfl_xor(tot, off);
    if ((tid & 63) == 0) sred[tid >> 6][0] = tot;
    __syncthreads();
    float denom = sred[0][0] + sred[1][0];
    float wj = (denom > 0.0f) ? (ptf / denom) : 0.0f;
    __syncthreads();

    float vals[18];
#pragma unroll
    for (int f = 0; f < 18; ++f) vals[f] = wj * yn[f];
#pragma unroll
    for (int f = 0; f < 18; ++f) {
        float s = vals[f];
#pragma unroll
        for (int off = 32; off; off >>= 1) s += __shfl_xor(s, off);
        vals[f] = s;
    }
    if ((tid & 63) == 0) {
#pragma unroll
        for (int f = 0; f < 18; ++f) sred[tid >> 6][f] = vals[f];
    }
    __syncthreads();
    if (tid < 18) xg[tid] = sred[0][tid] + sred[1][tid];
    __syncthreads();

    if (tid < 32) {
        float h = b0[tid];
#pragma unroll
        for (int k = 0; k < 16; ++k) h = fmaf(xg[k], w0[k * 32 + tid], h);
        h = fmaxf(h, 0.01f * h);
        h1s[tid] = h;
    }
    __syncthreads();
    if (tid < 32) {
        float h = b1[tid];
#pragma unroll
        for (int k = 0; k < 32; ++k) h = fmaf(h1s[k], w1[k * 32 + tid], h);
        h = fmaxf(h, 0.01f * h);
        float p = h * w2[tid];
#pragma unroll
        for (int off = 16; off; off >>= 1) p += __shfl_xor(p, off, 32);
        if (tid == 0) {
            out[b * 3 + 0] = 1.0f / (1.0f + expf(-(p + b2[0])));
            out[b * 3 + 1] = xg[16];
            out[b * 3 + 2] = xg[17];
        }
    }
}

extern "C" void kernel_launch(void* const* d_in, const int* in_sizes, int n_in,
                              void* d_out, int out_size, void* d_ws, size_t ws_size,
                              hipStream_t stream) {
    const float* pt    = (const float*)d_in[0];
    const float* ang   = (const float*)d_in[1];
    const float* c0_w0 = (const float*)d_in[2];
    const float* c0_b0 = (const float*)d_in[3];
    const float* c0_w1 = (const float*)d_in[4];
    const float* c0_b1 = (const float*)d_in[5];
    const float* c1_w0 = (const float*)d_in[6];
    const float* c1_b0 = (const float*)d_in[7];
    const float* c1_w1 = (const float*)d_in[8];
    const float* c1_b1 = (const float*)d_in[9];
    const float* r_w0  = (const float*)d_in[10];
    const float* r_b0  = (const float*)d_in[11];
    const float* r_w1  = (const float*)d_in[12];
    const float* r_b1  = (const float*)d_in[13];
    const float* r_w2  = (const float*)d_in[14];
    const float* r_b2  = (const float*)d_in[15];
    float* out = (float*)d_out;
    float* ws = (float*)d_ws;

    float* ang1 = ws;                          // BN*2
    float* u1   = ang1 + (size_t)BN * 2;       // BN*16
    float* v1   = u1 + (size_t)BN * 16;        // BN*16
    float* y1   = v1 + (size_t)BN * 16;        // BN*18

    hipLaunchKernelGGL((conv_kernel<0>), dim3(BN / 4), dim3(256), 0, stream,
                       ang, (const float*)nullptr, (const float*)nullptr,
                       c0_w0, c0_b0, c0_w1, c0_b1,
                       c1_w0, c1_b0, u1, v1, ang1, (float*)nullptr);
    hipLaunchKernelGGL((conv_kernel<1>), dim3(BN / 4), dim3(256), 0, stream,
                       ang1, u1, v1,
                       c1_w0, (const float*)nullptr, c1_w1, c1_b1,
                       (const float*)nullptr, (const float*)nullptr,
                       (float*)nullptr, (float*)nullptr, (float*)nullptr, y1);
    hipLaunchKernelGGL(readout_kernel, dim3(BB), dim3(128), 0, stream,
                       pt, y1, r_w0, r_b0, r_w1, r_b1, r_w2, r_b2, out);
}

// Round 6
// 30.210 us; speedup vs baseline: 1.4320x; 1.1624x over previous
//
#include <hip/hip_runtime.h>
#include <math.h>

// SMEFTNet forward. B=128, N=128, H=16.  "Config Y": 4 nodes per wave.
// lane = g*16 + t:  g = node-subgroup (wave handles nodes wid*4+g), t = channel.
// j-loop: 8 iters, lane handles pair (node_g, j = 16*jj + t).
// Reduce: 4-step DPP tree within 16-lane rows + ds_bpermute broadcast from
// lane (l|15) -> every lane gets its node's channel sums. deg = 17th chain.
// conv0 epilogue: 2nd layer (one FMA pass, all lanes), gamma pass (SGPR w1
// col 16), rotation per-lane (t==0 stores float4 ang1 = re,im,inv), proj to
// u1/v1 via LDS h-exchange (same-wave, no barrier) + 2 full-wave passes.
// conv1 epilogue: same + per-wave readout partials (xor16 swizzle + xor32
// shfl over groups) -> part[4096][20]. K3: 1 wave/batch sums 32 partial rows,
// then the 16->32->32->1 readout MLP.

#define BB 128
#define NN 128
#define BN (BB * NN)

typedef float f32x2 __attribute__((ext_vector_type(2)));

__device__ __forceinline__ f32x2 pk2(float s) { f32x2 r; r[0] = s; r[1] = s; return r; }
__device__ __forceinline__ f32x2 pkfma(f32x2 a, f32x2 b, f32x2 c) {
    return __builtin_elementwise_fma(a, b, c);
}
__device__ __forceinline__ f32x2 pkmax(f32x2 a, f32x2 b) {
    return __builtin_elementwise_max(a, b);
}

template <int CTRL>
__device__ __forceinline__ float dpp_add(float x) {
    int tmp = __builtin_amdgcn_update_dpp(0, __float_as_int(x), CTRL, 0xF, 0xF, true);
    return x + __int_as_float(tmp);
}

// Sum within each 16-lane row; result valid in lane (l|15) of each row.
__device__ __forceinline__ float grp16_sum(float x) {
    x = dpp_add<0xB1>(x);   // quad_perm [1,0,3,2]  (xor 1)
    x = dpp_add<0x4E>(x);   // quad_perm [2,3,0,1]  (xor 2)
    x = dpp_add<0x114>(x);  // row_shr:4
    x = dpp_add<0x118>(x);  // row_shr:8
    return x;
}

__device__ __forceinline__ float bcast_grp(float x, int bidx) {
    return __int_as_float(__builtin_amdgcn_ds_bpermute(bidx, __float_as_int(x)));
}

// ---------------- K1: conv0 + fused proj for conv1 ----------------
__global__ __launch_bounds__(256) void conv0_kernel(
    const float* __restrict__ ang,   // (B,N,2)
    const float* __restrict__ w0,    // c0_w0 (5,16)
    const float* __restrict__ b0,    // (16)
    const float* __restrict__ w1,    // c0_w1 (16,17)
    const float* __restrict__ b1,    // (17)
    const float* __restrict__ nw0,   // c1_w0 (50,16)
    const float* __restrict__ nb0,   // c1_b0 (16)
    float* __restrict__ ang1,        // (BN,4): re,im,inv,0
    float* __restrict__ u1,          // (BN,16)
    float* __restrict__ v1)          // (BN,16)
{
    const int tid  = threadIdx.x;
    const int lane = tid & 63;
    const int wid  = tid >> 6;
    const int t    = lane & 15;      // channel / j-sub-index
    const int g    = lane >> 4;      // node subgroup 0..3
    const int ni   = blockIdx.x * 16 + wid * 4 + g;
    const int base = (blockIdx.x >> 3) << 7;   // batch start node

    __shared__ float hls[16][17];

    // my node
    const float2 ai = ((const float2*)ang)[ni];
    const float r2i = fmaf(ai.x, ai.x, ai.y * ai.y);
    const float abszi = __builtin_amdgcn_sqrtf(r2i);
    const float invi  = __builtin_amdgcn_rsqf(r2i);

    // layer-0 row constants (wave-uniform -> s_load) + per-lane u0b
    f32x2 u0b2[8], q02[8], wc2[8], ws2[8];
    #pragma unroll
    for (int p = 0; p < 8; ++p) {
        f32x2 wa  = *(const f32x2*)(w0 + 2 * p);
        f32x2 wb  = *(const f32x2*)(w0 + 16 + 2 * p);
        f32x2 wcv = *(const f32x2*)(w0 + 32 + 2 * p);
        f32x2 bb  = *(const f32x2*)(b0 + 2 * p);
        u0b2[p] = pkfma(pk2(abszi), wa - wcv, bb);   // absz_i*(Wa-Wc)+b0
        q02[p]  = wb + wcv;                          // Wb+Wc
        wc2[p]  = *(const f32x2*)(w0 + 48 + 2 * p);
        ws2[p]  = *(const f32x2*)(w0 + 64 + 2 * p);
    }

    // prefetch w1 column t (per-lane) and gamma column (uniform)
    float w1row[16], w1g[16];
    #pragma unroll
    for (int k = 0; k < 16; ++k) {
        w1row[k] = w1[k * 17 + t];
        w1g[k]   = w1[k * 17 + 16];
    }
    const float b1t = b1[t], b1g = b1[16];

    // prefetch + combine proj weights: output o = lane&31 (k = o&15, u/v half)
    const int o   = lane & 31;
    const int kk  = o & 15;
    const bool isU = (o < 16);
    float wk[16];
    {
        const int off = isU ? 0 : 256;
        #pragma unroll
        for (int c = 0; c < 16; ++c) {
            float a_ = nw0[off + c * 16 + kk];
            float c_ = nw0[512 + c * 16 + kk];
            wk[c] = isU ? (a_ - c_) : (a_ + c_);
        }
    }
    const float accb = isU ? nb0[kk] : 0.0f;

    // j-loop: 8 iters, j = 16*jj + t
    f32x2 A2[8];
    #pragma unroll
    for (int p = 0; p < 8; ++p) A2[p] = pk2(0.0f);
    float degf = 0.0f;

    #pragma unroll 4
    for (int jj = 0; jj < 8; ++jj) {
        const float2 aj = ((const float2*)ang)[base + jj * 16 + t];
        const float r2j = fmaf(aj.x, aj.x, aj.y * aj.y);
        const float abszj = __builtin_amdgcn_sqrtf(r2j);
        const float ivj   = __builtin_amdgcn_rsqf(r2j);
        const float dre = ai.x - aj.x, dim = ai.y - aj.y;
        const float d2 = fmaf(dre, dre, dim * dim);
        const float adjf = (d2 <= 0.16f) ? 1.0f : 0.0f;
        degf += adjf;
        const float inv = fminf(invi * ivj, 1e12f);
        const f32x2 cos2 = pk2(fmaf(ai.x, aj.x, ai.y * aj.y) * inv);
        const f32x2 sin2 = pk2(fmaf(ai.y, aj.x, -(ai.x * aj.y)) * inv);
        const f32x2 ab2 = pk2(abszj);
        const f32x2 adj2 = pk2(adjf);
        #pragma unroll
        for (int p = 0; p < 8; ++p) {
            f32x2 z = pkfma(ab2, q02[p], u0b2[p]);
            z = pkfma(cos2, wc2[p], z);
            z = pkfma(sin2, ws2[p], z);
            f32x2 a = pkmax(z, z * 0.01f);
            A2[p] = pkfma(a, adj2, A2[p]);
        }
    }

    // reduce: 17 chains, 4-step DPP + bpermute broadcast from lane (l|15)
    const int bidx = (lane | 15) << 2;
    float Ak[16];
    #pragma unroll
    for (int p = 0; p < 8; ++p) {
        Ak[2 * p]     = bcast_grp(grp16_sum(A2[p][0]), bidx);
        Ak[2 * p + 1] = bcast_grp(grp16_sum(A2[p][1]), bidx);
    }
    const float degA = bcast_grp(grp16_sum(degf), bidx);
    const float invdeg = __builtin_amdgcn_rcpf(degA);

    // 2nd MLP layer: channel t (per-lane weights) + gamma (SGPR weights)
    float s = 0.0f, sg = 0.0f;
    #pragma unroll
    for (int k = 0; k < 16; ++k) {
        s  = fmaf(Ak[k], w1row[k], s);
        sg = fmaf(Ak[k], w1g[k], sg);
    }
    const float mt    = fmaf(s, invdeg, b1t);
    const float gamma = fmaf(sg, invdeg, b1g);

    // rotation (v_cos/v_sin take revolutions); norm preserved -> store invi
    {
        const float gf = gamma - floorf(gamma);
        const float cs = __builtin_amdgcn_cosf(gf);
        const float sn = __builtin_amdgcn_sinf(gf);
        const float re2 = cs * ai.x - sn * ai.y;
        const float im2 = fmaf(sn, ai.x, cs * ai.y);
        if (t == 0) ((float4*)ang1)[ni] = make_float4(re2, im2, invi, 0.0f);
    }

    // h-exchange (same-wave LDS, no barrier needed)
    hls[wid * 4 + g][t] = mt;

    // proj: 2 passes x 64 lanes = 128 outputs (4 nodes x (16 u + 16 v))
    #pragma unroll
    for (int p = 0; p < 2; ++p) {
        const int nl = (lane >> 5) + 2 * p;       // node local 0..3
        const int node = wid * 4 + nl;
        float acc = accb;
        #pragma unroll
        for (int c = 0; c < 16; ++c) acc = fmaf(hls[node][c], wk[c], acc);
        const int nig = blockIdx.x * 16 + nl;
        const int nout = (blockIdx.x * 16 + node);
        (void)nig;
        if (isU) u1[nout * 16 + kk] = acc;
        else     v1[nout * 16 + kk] = acc;
    }
}

// ---------------- K2: conv1 + per-wave readout partials ----------------
__global__ __launch_bounds__(256) void conv1_kernel(
    const float* __restrict__ pt,    // (B,N)
    const float* __restrict__ ang1,  // (BN,4): re,im,inv,0
    const float* __restrict__ u1,    // (BN,16)
    const float* __restrict__ v1,    // (BN,16)
    const float* __restrict__ w0,    // c1_w0 (50,16)
    const float* __restrict__ w1,    // c1_w1 (16,17)
    const float* __restrict__ b1,    // (17)
    float* __restrict__ part)        // (4096,20): [0..15]=sum pt*m, 16=re,17=im,18=sum pt
{
    const int tid  = threadIdx.x;
    const int lane = tid & 63;
    const int wid  = tid >> 6;
    const int t    = lane & 15;
    const int g    = lane >> 4;
    const int ni   = blockIdx.x * 16 + wid * 4 + g;
    const int base = (blockIdx.x >> 3) << 7;

    // my node
    const float4 a4 = ((const float4*)ang1)[ni];
    const float rei = a4.x, imi = a4.y, invi = a4.z;
    const float ptf = pt[ni];

    f32x2 u0b2[8], wc2[8], ws2[8];
    {
        const float4* ug = (const float4*)(u1 + (size_t)ni * 16);
        float4 q0 = ug[0], q1 = ug[1], q2 = ug[2], q3 = ug[3];
        u0b2[0][0] = q0.x; u0b2[0][1] = q0.y; u0b2[1][0] = q0.z; u0b2[1][1] = q0.w;
        u0b2[2][0] = q1.x; u0b2[2][1] = q1.y; u0b2[3][0] = q1.z; u0b2[3][1] = q1.w;
        u0b2[4][0] = q2.x; u0b2[4][1] = q2.y; u0b2[5][0] = q2.z; u0b2[5][1] = q2.w;
        u0b2[6][0] = q3.x; u0b2[6][1] = q3.y; u0b2[7][0] = q3.z; u0b2[7][1] = q3.w;
    }
    #pragma unroll
    for (int p = 0; p < 8; ++p) {
        wc2[p] = *(const f32x2*)(w0 + 768 + 2 * p);
        ws2[p] = *(const f32x2*)(w0 + 784 + 2 * p);
    }

    float w1row[16], w1g[16];
    #pragma unroll
    for (int k = 0; k < 16; ++k) {
        w1row[k] = w1[k * 17 + t];
        w1g[k]   = w1[k * 17 + 16];
    }
    const float b1t = b1[t], b1g = b1[16];

    f32x2 A2[8];
    #pragma unroll
    for (int p = 0; p < 8; ++p) A2[p] = pk2(0.0f);
    float degf = 0.0f;

    #pragma unroll 4
    for (int jj = 0; jj < 8; ++jj) {
        const int j = base + jj * 16 + t;
        const float4 aj = ((const float4*)ang1)[j];
        f32x2 vj2[8];
        {
            const float4* vg = (const float4*)(v1 + (size_t)j * 16);
            float4 q0 = vg[0], q1 = vg[1], q2 = vg[2], q3 = vg[3];
            vj2[0][0] = q0.x; vj2[0][1] = q0.y; vj2[1][0] = q0.z; vj2[1][1] = q0.w;
            vj2[2][0] = q1.x; vj2[2][1] = q1.y; vj2[3][0] = q1.z; vj2[3][1] = q1.w;
            vj2[4][0] = q2.x; vj2[4][1] = q2.y; vj2[5][0] = q2.z; vj2[5][1] = q2.w;
            vj2[6][0] = q3.x; vj2[6][1] = q3.y; vj2[7][0] = q3.z; vj2[7][1] = q3.w;
        }
        const float dre = rei - aj.x, dim = imi - aj.y;
        const float d2 = fmaf(dre, dre, dim * dim);
        const float adjf = (d2 <= 0.16f) ? 1.0f : 0.0f;
        degf += adjf;
        const float inv = fminf(invi * aj.z, 1e12f);
        const f32x2 cos2 = pk2(fmaf(rei, aj.x, imi * aj.y) * inv);
        const f32x2 sin2 = pk2(fmaf(imi, aj.x, -(rei * aj.y)) * inv);
        const f32x2 adj2 = pk2(adjf);
        #pragma unroll
        for (int p = 0; p < 8; ++p) {
            f32x2 z = u0b2[p] + vj2[p];
            z = pkfma(cos2, wc2[p], z);
            z = pkfma(sin2, ws2[p], z);
            f32x2 a = pkmax(z, z * 0.01f);
            A2[p] = pkfma(a, adj2, A2[p]);
        }
    }

    const int bidx = (lane | 15) << 2;
    float Ak[16];
    #pragma unroll
    for (int p = 0; p < 8; ++p) {
        Ak[2 * p]     = bcast_grp(grp16_sum(A2[p][0]), bidx);
        Ak[2 * p + 1] = bcast_grp(grp16_sum(A2[p][1]), bidx);
    }
    const float degA = bcast_grp(grp16_sum(degf), bidx);
    const float invdeg = __builtin_amdgcn_rcpf(degA);

    float s = 0.0f, sg = 0.0f;
    #pragma unroll
    for (int k = 0; k < 16; ++k) {
        s  = fmaf(Ak[k], w1row[k], s);
        sg = fmaf(Ak[k], w1g[k], sg);
    }
    const float mt    = fmaf(s, invdeg, b1t);
    const float gamma = fmaf(sg, invdeg, b1g);

    const float gf = gamma - floorf(gamma);
    const float cs = __builtin_amdgcn_cosf(gf);
    const float sn = __builtin_amdgcn_sinf(gf);
    const float re2 = cs * rei - sn * imi;
    const float im2 = fmaf(sn, rei, cs * imi);

    // per-wave readout partials: sum over the wave's 4 nodes.
    float pm  = ptf * mt;     // per-channel t
    float pre = ptf * re2;    // uniform within group
    float pim = ptf * im2;
    float ppt = ptf;
    // cross-group sum: xor16 (ds_swizzle) + xor32 (shfl)
    pm  += __int_as_float(__builtin_amdgcn_ds_swizzle(__float_as_int(pm),  0x401F));
    pre += __int_as_float(__builtin_amdgcn_ds_swizzle(__float_as_int(pre), 0x401F));
    pim += __int_as_float(__builtin_amdgcn_ds_swizzle(__float_as_int(pim), 0x401F));
    ppt += __int_as_float(__builtin_amdgcn_ds_swizzle(__float_as_int(ppt), 0x401F));
    pm  += __shfl_xor(pm, 32);
    pre += __shfl_xor(pre, 32);
    pim += __shfl_xor(pim, 32);
    ppt += __shfl_xor(ppt, 32);

    float* po = part + (size_t)(blockIdx.x * 4 + wid) * 20;
    if (lane < 16)       po[lane] = pm;
    else if (lane == 16) po[16] = pre;
    else if (lane == 17) po[17] = pim;
    else if (lane == 18) po[18] = ppt;
}

// ---------------- K3: final readout (1 wave per batch) ----------------
__global__ __launch_bounds__(64) void readout_kernel(
    const float* __restrict__ part,  // (4096,20)
    const float* __restrict__ w0, const float* __restrict__ b0,  // (16,32),(32)
    const float* __restrict__ w1, const float* __restrict__ b1,  // (32,32),(32)
    const float* __restrict__ w2, const float* __restrict__ b2,  // (32,1),(1)
    float* __restrict__ out) {
    const int b = blockIdx.x;
    const int t = threadIdx.x;

    __shared__ float sbuf[19];
    __shared__ float xg[18];
    __shared__ float h1r[32];

    if (t < 19) {
        float s0 = 0.0f, s1 = 0.0f, s2 = 0.0f, s3 = 0.0f;
        const float* pb = part + (size_t)b * 32 * 20 + t;
        #pragma unroll
        for (int r = 0; r < 32; r += 4) {
            s0 += pb[(r + 0) * 20];
            s1 += pb[(r + 1) * 20];
            s2 += pb[(r + 2) * 20];
            s3 += pb[(r + 3) * 20];
        }
        sbuf[t] = (s0 + s1) + (s2 + s3);
    }
    // same wave: LDS ops are in-order, no barrier needed
    const float invd = __builtin_amdgcn_rcpf(sbuf[18]);
    if (t < 18) xg[t] = sbuf[t] * invd;

    if (t < 32) {
        float h = b0[t];
        #pragma unroll
        for (int k = 0; k < 16; ++k) h = fmaf(xg[k], w0[k * 32 + t], h);
        h = fmaxf(h, 0.01f * h);
        h1r[t] = h;
    }
    if (t < 32) {
        float h = b1[t];
        #pragma unroll
        for (int k = 0; k < 32; ++k) h = fmaf(h1r[k], w1[k * 32 + t], h);
        h = fmaxf(h, 0.01f * h);
        float p = h * w2[t];
        #pragma unroll
        for (int off = 16; off; off >>= 1) p += __shfl_xor(p, off);
        if (t == 0) {
            out[b * 3 + 0] = 1.0f / (1.0f + expf(-(p + b2[0])));
            out[b * 3 + 1] = xg[16];
            out[b * 3 + 2] = xg[17];
        }
    }
}

extern "C" void kernel_launch(void* const* d_in, const int* in_sizes, int n_in,
                              void* d_out, int out_size, void* d_ws, size_t ws_size,
                              hipStream_t stream) {
    const float* pt    = (const float*)d_in[0];
    const float* ang   = (const float*)d_in[1];
    const float* c0_w0 = (const float*)d_in[2];
    const float* c0_b0 = (const float*)d_in[3];
    const float* c0_w1 = (const float*)d_in[4];
    const float* c0_b1 = (const float*)d_in[5];
    const float* c1_w0 = (const float*)d_in[6];
    const float* c1_b0 = (const float*)d_in[7];
    const float* c1_w1 = (const float*)d_in[8];
    const float* c1_b1 = (const float*)d_in[9];
    const float* r_w0  = (const float*)d_in[10];
    const float* r_b0  = (const float*)d_in[11];
    const float* r_w1  = (const float*)d_in[12];
    const float* r_b1  = (const float*)d_in[13];
    const float* r_w2  = (const float*)d_in[14];
    const float* r_b2  = (const float*)d_in[15];
    float* out = (float*)d_out;
    float* ws = (float*)d_ws;

    float* ang1  = ws;                         // BN*4
    float* u1    = ang1 + (size_t)BN * 4;      // BN*16
    float* v1    = u1 + (size_t)BN * 16;       // BN*16
    float* partb = v1 + (size_t)BN * 16;       // 4096*20

    hipLaunchKernelGGL(conv0_kernel, dim3(BN / 16), dim3(256), 0, stream,
                       ang, c0_w0, c0_b0, c0_w1, c0_b1, c1_w0, c1_b0,
                       ang1, u1, v1);
    hipLaunchKernelGGL(conv1_kernel, dim3(BN / 16), dim3(256), 0, stream,
                       pt, ang1, u1, v1, c1_w0, c1_w1, c1_b1, partb);
    hipLaunchKernelGGL(readout_kernel, dim3(BB), dim3(64), 0, stream,
                       partb, r_w0, r_b0, r_w1, r_b1, r_w2, r_b2, out);
}